// Round 6
// baseline (3155.865 us; speedup 1.0000x reference)
//
#include <hip/hip_runtime.h>
#include <hip/hip_fp16.h>

// Sinkhorn OT: 64 chains, d=768, lam=0.01, 100 iters + final LSE.
// Round 6 = round 4 architecture + BOUNDED spin-waits (anti-hang insurance):
// two consecutive container failures were either infra or an un-diagnosable
// stall; bounded polls (cap ~4ms each, 400x expected wait) convert any stall
// into a fast wrong-answer verdict with counters instead of a dead container.
// Architecture: reduce-scatter across 8 blocks/group, local-max scales,
// flag-based sc1 exchange, 2-chain stagger; e vectors fp32 in LDS
// (round-2-validated numerics: fp16 K x fp32 e, fp32 accumulate).

#define D        768
#define SEG      96
#define QP       12
#define NITERS   100
#define INV_LAM  100.0f
#define C14      9.70406052784f   // 14*ln2 (2^14 fp16 scale folded into offsets)
#define SCALE14  16384.0f
#define LOG768   6.64385618977f
#define SPIN_CAP 16384            // ~4ms cap; expected waits ~10us (400x margin)

// ---- agent-scope relaxed ops (sc1; coherence point) ----
static __device__ __forceinline__ void st_agent(float* p, float v) {
    __hip_atomic_store(p, v, __ATOMIC_RELAXED, __HIP_MEMORY_SCOPE_AGENT);
}
static __device__ __forceinline__ float ld_agent(const float* p) {
    return __hip_atomic_load((float*)p, __ATOMIC_RELAXED, __HIP_MEMORY_SCOPE_AGENT);
}
static __device__ __forceinline__ void st_flag(int* p, int v) {
    __hip_atomic_store(p, v, __ATOMIC_RELAXED, __HIP_MEMORY_SCOPE_AGENT);
}
static __device__ __forceinline__ int ld_flag(const int* p) {
    return __hip_atomic_load((int*)p, __ATOMIC_RELAXED, __HIP_MEMORY_SCOPE_AGENT);
}

// ---- partial matvec: out[tid] = sum over 96 local elems (12 quads) ----
// mp = matrix base + 12p*D + tid (quad t at mp[t*D]); ef = fp32 e[96] in LDS.
static __device__ __forceinline__ float mv_part(const uint4* __restrict__ mp,
                                                const float* __restrict__ ef) {
    const float4* e4 = (const float4*)ef;
    float a0 = 0.f, a1 = 0.f, a2 = 0.f, a3 = 0.f;
    #pragma unroll
    for (int t = 0; t < QP; ++t) {
        uint4 kv = mp[(size_t)t * D];
        float4 x = e4[2 * t];
        float4 y = e4[2 * t + 1];
        float2 k0 = __half22float2(__builtin_bit_cast(__half2, kv.x));
        float2 k1 = __half22float2(__builtin_bit_cast(__half2, kv.y));
        float2 k2 = __half22float2(__builtin_bit_cast(__half2, kv.z));
        float2 k3 = __half22float2(__builtin_bit_cast(__half2, kv.w));
        a0 = fmaf(k0.x, x.x, a0); a1 = fmaf(k0.y, x.y, a1);
        a2 = fmaf(k1.x, x.z, a2); a3 = fmaf(k1.y, x.w, a3);
        a0 = fmaf(k2.x, y.x, a0); a1 = fmaf(k2.y, y.y, a1);
        a2 = fmaf(k3.x, y.z, a2); a3 = fmaf(k3.y, y.w, a3);
    }
    return (a0 + a1) + (a2 + a3);
}

// ---- post: publish 768 partials + local scale, then flag := tag ----
static __device__ __forceinline__ void post_seg(float* xw, float val, float* cw,
                                                float cu, int* flw, int tag, int tid) {
    st_agent(xw, val);
    if (tid == 0) st_agent(cw, cu);
    asm volatile("s_waitcnt vmcnt(0)" ::: "memory");
    __syncthreads();
    if (tid == 0) st_flag(flw, tag);
}

// ---- poll: lanes 0..63 wait (BOUNDED) for writer (lane&7)'s flag >= tag ----
static __device__ __forceinline__ void poll_flags(const int* flr, int tag, int tid) {
    if (tid < 64) {
        int spin = 0;
        while (ld_flag(flr) < tag && spin < SPIN_CAP) {
            __builtin_amdgcn_s_sleep(2);
            ++spin;
        }
    }
    __syncthreads();
    __atomic_signal_fence(__ATOMIC_ACQUIRE);
}

// ---- gather core: log( sum_p x_p * e^{cu_p} ) with stable rescale ----
// All 64 lanes active at every shuffle (no divergence).
static __device__ __forceinline__ float gather_logsum(const float* xr, const float* cr) {
    float x = ld_agent(xr);
    float cu = ld_agent(cr);
    float cs = cu;
    #pragma unroll
    for (int o = 1; o < 8; o <<= 1) cs = fmaxf(cs, __shfl_xor(cs, o));
    float t = x * __expf(cu - cs);
    #pragma unroll
    for (int o = 1; o < 8; o <<= 1) t += __shfl_xor(t, o);
    return __logf(t) + cs;
}

// ---- gather: new log-vec at own 96 idx, local max, fp32 e -> LDS ----
static __device__ __forceinline__ void gather_step(const float* xr, const float* cr,
                                                   float logmn, float coffj, int tid,
                                                   float* s_red, float* e_out,
                                                   float& lx_o, float& cloc_o) {
    float lx = logmn - (gather_logsum(xr, cr) + coffj);
    float m = lx;
    #pragma unroll
    for (int o = 8; o < 64; o <<= 1) m = fmaxf(m, __shfl_xor(m, o));
    if ((tid & 63) == 0) s_red[tid >> 6] = m;
    __syncthreads();
    float mm = s_red[0];
    #pragma unroll
    for (int w = 1; w < 12; ++w) mm = fmaxf(mm, s_red[w]);
    float e = __expf(lx - mm);                 // computed by ALL lanes
    if ((tid & 7) == 0) e_out[tid >> 3] = e;   // plain per-lane store, no shfl
    lx_o = lx; cloc_o = mm;
    __syncthreads();
}

// ---- LSE over own 96 (values duplicated x8 across pp) -> (m, z) ----
static __device__ __forceinline__ float2 lse96(float negs, float* s_red, int tid) {
    int pp = tid & 7;
    float m = negs;
    #pragma unroll
    for (int o = 8; o < 64; o <<= 1) m = fmaxf(m, __shfl_xor(m, o));
    __syncthreads();
    if ((tid & 63) == 0) s_red[tid >> 6] = m;
    __syncthreads();
    float mm = s_red[0];
    #pragma unroll
    for (int w = 1; w < 12; ++w) mm = fmaxf(mm, s_red[w]);
    float zv = (pp == 0) ? __expf(negs - mm) : 0.f;
    #pragma unroll
    for (int o = 1; o < 64; o <<= 1) zv += __shfl_xor(zv, o);
    __syncthreads();
    if ((tid & 63) == 0) s_red[tid >> 6] = zv;
    __syncthreads();
    float z = s_red[0];
    #pragma unroll
    for (int w = 1; w < 12; ++w) z += s_red[w];
    return make_float2(mm, z);
}

// ---- prep: fp16 K-hat (per-column offsets), zero flags ----
__global__ void prep_cols(const float* __restrict__ dist, uint4* __restrict__ Kq,
                          float* __restrict__ cK2, float* __restrict__ cF2,
                          int* __restrict__ flg) {
    int T = blockIdx.x * blockDim.x + threadIdx.x;
    if (T < 1024) flg[T] = 0;
    int j = T >> 3, w = T & 7;
    float mc = 3.402823e38f, mf = -3.402823e38f;
    for (int i = 96 * w; i < 96 * w + 96; ++i) {
        float d = dist[(size_t)i * D + j];
        mc = fminf(mc, d);
        mf = fmaxf(mf, __logf(d) - d * INV_LAM);
    }
    #pragma unroll
    for (int o = 1; o < 8; o <<= 1) { mc = fminf(mc, __shfl_xor(mc, o)); mf = fmaxf(mf, __shfl_xor(mf, o)); }
    if (w == 0) { cK2[j] = -mc * INV_LAM - C14; cF2[j] = mf; }
    for (int t = 0; t < QP; ++t) {
        int q = QP * w + t;
        union { uint4 u4; __half2 h2[8]; } pk;
        #pragma unroll
        for (int r = 0; r < 4; ++r) {
            float d0 = dist[(size_t)(8 * q + 2 * r) * D + j];
            float d1 = dist[(size_t)(8 * q + 2 * r + 1) * D + j];
            pk.h2[r] = __halves2half2(__float2half(__expf((mc - d0) * INV_LAM) * SCALE14),
                                      __float2half(__expf((mc - d1) * INV_LAM) * SCALE14));
        }
        Kq[(size_t)q * D + j] = pk.u4;
    }
}

// ---- prep: fp16 K^T-hat (per-row offsets) ----
__global__ void prep_rows(const float* __restrict__ dist, uint4* __restrict__ KTq,
                          float* __restrict__ cKT2) {
    int T = blockIdx.x * blockDim.x + threadIdx.x;
    int i = T >> 3, w = T & 7;
    const float* row = dist + (size_t)i * D;
    float mr = 3.402823e38f;
    for (int jj = 96 * w; jj < 96 * w + 96; ++jj) mr = fminf(mr, row[jj]);
    #pragma unroll
    for (int o = 1; o < 8; o <<= 1) mr = fminf(mr, __shfl_xor(mr, o));
    if (w == 0) cKT2[i] = -mr * INV_LAM - C14;
    for (int t = 0; t < QP; ++t) {
        int q = QP * w + t;
        union { uint4 u4; __half2 h2[8]; } pk;
        #pragma unroll
        for (int r = 0; r < 4; ++r) {
            float d0 = row[8 * q + 2 * r];
            float d1 = row[8 * q + 2 * r + 1];
            pk.h2[r] = __halves2half2(__float2half(__expf((mr - d0) * INV_LAM) * SCALE14),
                                      __float2half(__expf((mr - d1) * INV_LAM) * SCALE14));
        }
        KTq[(size_t)q * D + i] = pk.u4;
    }
}

// ---- main: 32 groups x 8 parts, 2 staggered chains per group ----
__global__ __launch_bounds__(768) void sink6(
    const float* __restrict__ mu, const float* __restrict__ nu,
    const float* __restrict__ dist,
    const uint4* __restrict__ Kq, const uint4* __restrict__ KTq,
    const float* __restrict__ cK2, const float* __restrict__ cKT2,
    const float* __restrict__ cF2,
    float* __restrict__ xbuf, float* __restrict__ cub,
    int* __restrict__ flg, float* __restrict__ fbuf,
    float* __restrict__ out) {
    __shared__ __align__(16) float s_eu[2][SEG];   // e^{lu - cu_loc}, fp32
    __shared__ __align__(16) float s_ev[2][SEG];   // e^{lv - cv_loc}, fp32
    __shared__ float s_red[12];
    __shared__ char s_pad[81920];   // LDS > 80KB => 1 block/CU => all 256 resident
    if (mu == nullptr) { s_pad[threadIdx.x] = 1; s_eu[0][0] = (float)s_pad[0]; }

    const int tid = threadIdx.x;
    const int p = blockIdx.x & 7, g = blockIdx.x >> 3;
    const int c0 = 2 * g;
    const int pp = tid & 7, jj = tid >> 3;
    const int jglob = p * SEG + jj;
    const int qc = tid / 96, jw = tid - 96 * qc;
    const int qoff = (qc * 8 + p) * SEG + jw;       // writer offset for column tid
    const int rdo = (p * 8 + pp) * SEG + jj;        // reader offset: writer pp, own elem

    const float lnu0 = __logf(nu[(size_t)c0 * D + jglob]);
    const float lnu1 = __logf(nu[(size_t)(c0 + 1) * D + jglob]);
    const float lmu0 = __logf(mu[(size_t)c0 * D + jglob]);
    const float lmu1 = __logf(mu[(size_t)(c0 + 1) * D + jglob]);
    const float cKg = cK2[jglob], cKTg = cKT2[jglob], cFg = cF2[jglob];
    const float cFt = cF2[tid];

    const uint4* Kv = Kq  + (size_t)(QP * p) * D + tid;   // own 96 rows (v-step)
    const uint4* Ku = KTq + (size_t)(QP * p) * D + tid;   // own 96 cols (u-step)

    const size_t r00 = ((size_t)(g * 2 + 0) * 2 + 0), r01 = r00 + 1;
    const size_t r10 = ((size_t)(g * 2 + 1) * 2 + 0), r11 = r10 + 1;
    float* const xw0e = xbuf + r00 * 6144 + qoff; float* const xw0o = xbuf + r01 * 6144 + qoff;
    float* const xw1e = xbuf + r10 * 6144 + qoff; float* const xw1o = xbuf + r11 * 6144 + qoff;
    const float* const xr0e = xbuf + r00 * 6144 + rdo; const float* const xr0o = xbuf + r01 * 6144 + rdo;
    const float* const xr1e = xbuf + r10 * 6144 + rdo; const float* const xr1o = xbuf + r11 * 6144 + rdo;
    float* const cw0e = cub + r00 * 8 + p; float* const cw0o = cub + r01 * 8 + p;
    float* const cw1e = cub + r10 * 8 + p; float* const cw1o = cub + r11 * 8 + p;
    const float* const cr0e = cub + r00 * 8 + pp; const float* const cr0o = cub + r01 * 8 + pp;
    const float* const cr1e = cub + r10 * 8 + pp; const float* const cr1o = cub + r11 * 8 + pp;
    int* const flw0 = flg + (g * 2 + 0) * 16 + p;
    int* const flw1 = flg + (g * 2 + 1) * 16 + p;
    const int* const flr0 = flg + (g * 2 + 0) * 16 + (tid & 7);
    const int* const flr1 = flg + (g * 2 + 1) * 16 + (tid & 7);

    // init: lu = -log768 everywhere -> local e_u = 1, scale = -log768
    if (tid < SEG) { s_eu[0][tid] = 1.f; s_eu[1][tid] = 1.f; }
    float r_cu0 = -LOG768, r_cu1 = -LOG768;
    float r_cv0 = 0.f, r_cv1 = 0.f, r_lv0 = 0.f, r_lv1 = 0.f, r_dump;
    int hs0 = 0, hs1 = 0;
    __syncthreads();

    for (int it = 0; it < NITERS; ++it) {
        // A: v matvec + post
        float SA = mv_part(Kv, s_eu[0]);
        ++hs0;
        post_seg((hs0 & 1) ? xw0o : xw0e, SA, (hs0 & 1) ? cw0o : cw0e, r_cu0, flw0, hs0, tid);
        // B: u gather from previous iteration (hides A's fabric latency)
        if (it > 0) {
            poll_flags(flr1, hs1, tid);
            gather_step((hs1 & 1) ? xr1o : xr1e, (hs1 & 1) ? cr1o : cr1e,
                        lmu1, cKTg, tid, s_red, s_eu[1], r_dump, r_cu1);
        }
        // B: v matvec + post
        float SB = mv_part(Kv, s_eu[1]);
        ++hs1;
        post_seg((hs1 & 1) ? xw1o : xw1e, SB, (hs1 & 1) ? cw1o : cw1e, r_cu1, flw1, hs1, tid);
        // A: v gather
        poll_flags(flr0, hs0, tid);
        gather_step((hs0 & 1) ? xr0o : xr0e, (hs0 & 1) ? cr0o : cr0e,
                    lnu0, cKg, tid, s_red, s_ev[0], r_lv0, r_cv0);
        // A: u matvec + post
        float TA = mv_part(Ku, s_ev[0]);
        ++hs0;
        post_seg((hs0 & 1) ? xw0o : xw0e, TA, (hs0 & 1) ? cw0o : cw0e, r_cv0, flw0, hs0, tid);
        // B: v gather
        poll_flags(flr1, hs1, tid);
        gather_step((hs1 & 1) ? xr1o : xr1e, (hs1 & 1) ? cr1o : cr1e,
                    lnu1, cKg, tid, s_red, s_ev[1], r_lv1, r_cv1);
        // B: u matvec + post
        float TB = mv_part(Ku, s_ev[1]);
        ++hs1;
        post_seg((hs1 & 1) ? xw1o : xw1e, TB, (hs1 & 1) ? cw1o : cw1e, r_cv1, flw1, hs1, tid);
        // A: u gather
        poll_flags(flr0, hs0, tid);
        gather_step((hs0 & 1) ? xr0o : xr0e, (hs0 & 1) ? cr0o : cr0e,
                    lmu0, cKTg, tid, s_red, s_eu[0], r_dump, r_cu0);
    }
    // B: final u gather
    poll_flags(flr1, hs1, tid);
    gather_step((hs1 & 1) ? xr1o : xr1e, (hs1 & 1) ? cr1o : cr1e,
                lmu1, cKTg, tid, s_red, s_eu[1], r_dump, r_cu1);

    // final partials: F-hat computed on the fly (fp32), both chains
    float FA = 0.f, FB = 0.f;
    const float* dp = dist + (size_t)(SEG * p) * D + tid;
    #pragma unroll 4
    for (int ii = 0; ii < SEG; ++ii) {
        float d = dp[(size_t)ii * D];
        float fh = __expf(__logf(d) - d * INV_LAM - cFt);
        FA = fmaf(fh, s_eu[0][ii], FA);
        FB = fmaf(fh, s_eu[1][ii], FB);
    }
    ++hs0;
    post_seg((hs0 & 1) ? xw0o : xw0e, FA, (hs0 & 1) ? cw0o : cw0e, r_cu0, flw0, hs0, tid);
    ++hs1;
    post_seg((hs1 & 1) ? xw1o : xw1e, FB, (hs1 & 1) ? cw1o : cw1e, r_cu1, flw1, hs1, tid);

    poll_flags(flr0, hs0, tid);
    float negs0 = r_lv0 + gather_logsum((hs0 & 1) ? xr0o : xr0e, (hs0 & 1) ? cr0o : cr0e) + cFg;
    float2 mzA = lse96(negs0, s_red, tid);
    poll_flags(flr1, hs1, tid);
    float negs1 = r_lv1 + gather_logsum((hs1 & 1) ? xr1o : xr1e, (hs1 & 1) ? cr1o : cr1e) + cFg;
    float2 mzB = lse96(negs1, s_red, tid);

    // per-part (m,z) -> group combine at part 0
    if (tid == 0) {
        float* fb = fbuf + (size_t)(g * 8 + p) * 4;
        st_agent(fb + 0, mzA.x); st_agent(fb + 1, mzA.y);
        st_agent(fb + 2, mzB.x); st_agent(fb + 3, mzB.y);
    }
    asm volatile("s_waitcnt vmcnt(0)" ::: "memory");
    __syncthreads();
    if (tid == 0) st_flag(flw0, hs0 + 1);
    if (p == 0) {
        poll_flags(flr0, hs0 + 1, tid);
        if (tid == 0) {
            float pm0[8], pz0[8], pm1[8], pz1[8];
            #pragma unroll
            for (int q = 0; q < 8; ++q) {
                const float* fq = fbuf + (size_t)(g * 8 + q) * 4;
                pm0[q] = ld_agent(fq + 0); pz0[q] = ld_agent(fq + 1);
                pm1[q] = ld_agent(fq + 2); pz1[q] = ld_agent(fq + 3);
            }
            float m0 = pm0[0], m1 = pm1[0];
            #pragma unroll
            for (int q = 1; q < 8; ++q) { m0 = fmaxf(m0, pm0[q]); m1 = fmaxf(m1, pm1[q]); }
            float z0 = 0.f, z1 = 0.f;
            #pragma unroll
            for (int q = 0; q < 8; ++q) {
                z0 += pz0[q] * __expf(pm0[q] - m0);
                z1 += pz1[q] * __expf(pm1[q] - m1);
            }
            out[c0] = __expf(m0) * z0;
            out[c0 + 1] = __expf(m1) * z1;
        }
    }
}

extern "C" void kernel_launch(void* const* d_in, const int* in_sizes, int n_in,
                              void* d_out, int out_size, void* d_ws, size_t ws_size,
                              hipStream_t stream) {
    const float* mu   = (const float*)d_in[0];
    const float* nu   = (const float*)d_in[1];
    const float* dist = (const float*)d_in[2];
    float* out = (float*)d_out;
    (void)in_sizes; (void)n_in; (void)out_size; (void)ws_size;

    char* w8 = (char*)d_ws;                       // ~5.53 MB total
    uint4* Kq   = (uint4*)(w8);                   // 1,179,648
    uint4* KTq  = (uint4*)(w8 + 1179648);         // 1,179,648
    float* cK2  = (float*)(w8 + 2359296);         // 3072
    float* cKT2 = (float*)(w8 + 2362368);         // 3072
    float* cF2  = (float*)(w8 + 2365440);         // 3072
    float* xbuf = (float*)(w8 + 2368512);         // 3,145,728 (128 regions x 6144 f)
    float* cub  = (float*)(w8 + 5514240);         // 4096
    int*   flg  = (int*)  (w8 + 5518336);         // 4096
    float* fbuf = (float*)(w8 + 5522432);         // 4096

    prep_cols<<<24, 256, 0, stream>>>(dist, Kq, cK2, cF2, flg);
    prep_rows<<<24, 256, 0, stream>>>(dist, KTq, cKT2);
    sink6<<<256, 768, 0, stream>>>(mu, nu, dist, Kq, KTq, cK2, cKT2, cF2,
                                   xbuf, cub, flg, fbuf, out);
}